// Round 9
// baseline (272.471 us; speedup 1.0000x reference)
//
#include <hip/hip_runtime.h>

// dense_image_warp: B=8, H=512, W=512, C=16, fp32.
//
// R8: cache-warming touch pass (no LDS). Model: the harness's 537MB fill
// between dispatches evicts ~half the image from L3; the ~60-77MB refetch is
// demanded by RANDOM 64B gathers at ~30% HBM row-buffer efficiency ->
// 76.6/0.3 + 131 streaming ~= 386MB-equiv at 6.3TB/s ~= 61-80us = measured.
// (Request-rate models falsified by arithmetic: 0.17 req/cy/CU at the TA,
// ~3 req/cy/XCD at TCC -- nothing close to saturation. R7's LDS staging
// regressed; R4 MLP regressed; R1/R3 locality null.)
// Fix: each block issues a dense ASCENDING-address touch of its 29x29-px
// slab footprint before gathering. HBM misses become sequential bursts;
// gathers then hit L1/L2. No barrier needed (MSHRs merge overlapping
// demand loads with in-flight warm misses); warming is side-effect-free,
// gather path byte-identical to R3. Warm results kept live via asm (rule
// #17: prevent DCE), consumed after the store so no extra waitcnt stall.
// Block = 1024 threads = 16x16 px tile; XCD-chunked bijective swizzle kept.

#define RAD 6
#define TS  16
#define SW  (TS + 2*RAD + 1)      // 29: rows/cols y0-6 .. y0+22 (iy+1 reach)
#define SROW (SW * 4)             // 116 float4 slots per slab row
#define SF4 (SW * SROW)           // 3364 float4 touches per block

__global__ __launch_bounds__(1024) void warp_kernel(
    const float* __restrict__ img,
    const float* __restrict__ flow,
    float* __restrict__ out)
{
    // XCD-chunked bijective swizzle (8192 blocks, 8 XCDs)
    const int bid = blockIdx.x;
    const int logical = ((bid & 7) << 10) + (bid >> 3);
    const int tx = logical & 31;          // tile x: 0..31
    const int ty = (logical >> 5) & 31;   // tile y: 0..31
    const int b  = logical >> 10;         // batch: 0..7

    const int x0 = tx << 4, y0 = ty << 4;
    const int ox = x0 - RAD, oy = y0 - RAD;

    // ---- warm: sequential ascending touch of this tile's gather footprint
    const float4* img4 = (const float4*)img;
    float wacc = 0.0f;
    #pragma unroll
    for (int k = 0; k < 4; ++k) {
        const int l = (int)threadIdx.x + (k << 10);
        if (l < SF4) {
            const int row   = l / SROW;            // 0..28 (magic-mul)
            const int u     = l - row * SROW;      // 0..115
            const int gy    = oy + row;
            const int gslot = (ox << 2) + u;       // float4 slot within row
            if ((unsigned)gy < 512u && (unsigned)gslot < 2048u) {
                const float4 v = img4[(((b << 9) + gy) << 11) + gslot];
                wacc += v.x;
            }
        }
    }
    // don't let later loads be hoisted above the warm stream
    asm volatile("" ::: "memory");

    // ---- per-thread flow load + address math
    const int t  = threadIdx.x;
    const int cg = t & 3;
    const int xx = (t >> 2) & 15;
    const int yy = t >> 6;
    const int x = x0 + xx, y = y0 + yy;
    const int pix = (((b << 9) + y) << 9) + x;

    const float2 f = ((const float2*)flow)[pix];
    const float qy = (float)y - f.x;
    const float qx = (float)x - f.y;
    float fy = floorf(qy); fy = fminf(fmaxf(fy, 0.0f), 510.0f);
    float fx = floorf(qx); fx = fminf(fmaxf(fx, 0.0f), 510.0f);
    const float ay = fminf(fmaxf(qy - fy, 0.0f), 1.0f);
    const float ax = fminf(fmaxf(qx - fx, 0.0f), 1.0f);
    const int iy = (int)fy;
    const int ix = (int)fx;

    // ---- gathers (now mostly L1/L2 hits)
    const float* p = img + ((size_t)((((b << 9) + iy) << 9) + ix)) * 16 + (cg << 2);
    const float4 tl = *(const float4*)(p);
    const float4 tr = *(const float4*)(p + 16);
    const float4 bl = *(const float4*)(p + 512 * 16);
    const float4 br = *(const float4*)(p + 512 * 16 + 16);

    float4 r;
    {
        float t0, u0;
        t0 = tl.x + ax * (tr.x - tl.x);
        u0 = bl.x + ax * (br.x - bl.x);
        r.x = t0 + ay * (u0 - t0);
        t0 = tl.y + ax * (tr.y - tl.y);
        u0 = bl.y + ax * (br.y - bl.y);
        r.y = t0 + ay * (u0 - t0);
        t0 = tl.z + ax * (tr.z - tl.z);
        u0 = bl.z + ax * (br.z - bl.z);
        r.z = t0 + ay * (u0 - t0);
        t0 = tl.w + ax * (tr.w - tl.w);
        u0 = bl.w + ax * (br.w - bl.w);
        r.w = t0 + ay * (u0 - t0);
    }

    ((float4*)out)[(pix << 2) + cg] = r;

    // keep the warm loads alive (rule #17); placed last so the implicit
    // vmcnt wait lands after all useful work (loads long since complete)
    asm volatile("" :: "v"(wacc));
}

extern "C" void kernel_launch(void* const* d_in, const int* in_sizes, int n_in,
                              void* d_out, int out_size, void* d_ws, size_t ws_size,
                              hipStream_t stream) {
    const float* img  = (const float*)d_in[0];
    const float* flow = (const float*)d_in[1];
    float* out = (float*)d_out;

    const int block = 1024;                       // 16x16 pixel tile, 4 cg/pixel
    const int grid = (8 * 512 * 512 * 4) / block; // 8192
    warp_kernel<<<grid, block, 0, stream>>>(img, flow, out);
}